// Round 13
// baseline (368.267 us; speedup 1.0000x reference)
//
#include <hip/hip_runtime.h>

#define N_PRE 1024
#define N_POST 2048
#define SEQ_LEN 4096

// Reference-verified numerics (R11 PASS): per C element two fp32 segment
// chains k in [0,512) and [512,1024), ascending, single accumulator each,
// combined rn(S1+S2). stim in {0,1} -> products exact -> FMA == mul+add.
// Scan: v = rn(rn(v*0.9f) + c), fire >= 1.0f, reset 0. DO NOT REORDER.
//
// Sparse (v6, PASS absmax 0.015625): skipping adds of exact +/-0.0 is
// BIT-IDENTICAL (acc starts +0.0; RN never yields -0.0 from a sum, so
// rn(acc + ±0) == acc). Walk the ascending per-t spike list: lo-chain k<512,
// hi-chain k>=512, write rn(lo+hi).
//
// v11 (PASS, 349us): XCD-slice pinning cut GEMM FETCH 130->12.4MB but dur
// only 136->125us: L2 misses were not the serializer. VALU 18%, HBM 5%,
// occupancy 77% -> exposed-latency/MLP bound (8 loads in flight, list-load
// address dependency ~200cyc). v12: BATCH16 (16 WT loads in flight, adds
// still list-ascending -> bit-identical) + 256-thr blocks (4 waves = 4
// consecutive t, same slice; 16384 -> 4096 blocks).
#define KSPLIT 512

__device__ __forceinline__ float opaque(float x) {
  asm volatile("" : "+v"(x));
  return x;
}

__device__ __forceinline__ float load_dyn(const void* p, size_t idx, bool isbf) {
  if (isbf) {
    const unsigned short b = ((const unsigned short*)p)[idx];
    return __uint_as_float(((unsigned int)b) << 16);
  }
  return ((const float*)p)[idx];
}

// Input-dtype sniff (established: weights fp32, stim bf16; kept for safety).
__device__ __forceinline__ int sniff_flags(const void* W, const void* S, int tid,
                                           int* flags_sh) {
  if (tid < 64) {
    const unsigned short* uw = (const unsigned short*)W;
    const float f = fabsf(__uint_as_float(((unsigned int)uw[tid * 2]) << 16));
    const bool big = !(f < 64.f);
    const unsigned long long wb = __ballot(big);
    const unsigned short* us = (const unsigned short*)S;
    int hit = 0;
    for (int j = 0; j < 64; ++j) hit |= (us[tid * 128 + 2 * j] == 0x3F80u) ? 1 : 0;
    const unsigned long long sb = __ballot(hit != 0);
    if (tid == 0) *flags_sh = ((wb == 0ull) ? 1 : 0) | ((sb != 0ull) ? 2 : 0);
  }
  __syncthreads();
  return *flags_sh;
}

// ---------------- WT build: W[n][k] -> WT[k][n] (fp32), LDS transpose -------
__global__ __launch_bounds__(256) void snn_wt_build(const void* __restrict__ W,
                                                    const void* __restrict__ S,
                                                    float* __restrict__ WT) {
  __shared__ float tile[64][65];
  __shared__ int flags_sh;
  const int tid = threadIdx.x;
  const int fl = sniff_flags(W, S, tid, &flags_sh);
  const bool w_bf = (fl & 1) != 0;
  const int k0 = blockIdx.x * 64;
  const int nn0 = blockIdx.y * 64;
  {
    const int r = tid >> 2;
    const int cq = tid & 3;
    if (!w_bf) {
      const float* Wf = (const float*)W;
#pragma unroll
      for (int p = 0; p < 4; ++p) {
        const int c = cq * 16 + p * 4;
        const float4 va = *(const float4*)&Wf[(size_t)(nn0 + r) * N_PRE + k0 + c];
        tile[c + 0][r] = va.x; tile[c + 1][r] = va.y;
        tile[c + 2][r] = va.z; tile[c + 3][r] = va.w;
      }
    } else {
#pragma unroll
      for (int p = 0; p < 4; ++p)
#pragma unroll
        for (int j = 0; j < 4; ++j) {
          const int c = cq * 16 + p * 4 + j;
          tile[c][r] = load_dyn(W, (size_t)(nn0 + r) * N_PRE + k0 + c, true);
        }
    }
  }
  __syncthreads();
  {
    const int kr = tid >> 2;
    const int nq = tid & 3;
#pragma unroll
    for (int p = 0; p < 4; ++p) {
      const int c = nq * 16 + p * 4;
      float4 o;
      o.x = tile[kr][c + 0]; o.y = tile[kr][c + 1];
      o.z = tile[kr][c + 2]; o.w = tile[kr][c + 3];
      *(float4*)&WT[(size_t)(k0 + kr) * N_POST + nn0 + c] = o;
    }
  }
}

// ---------------- mask build: stim -> MT[t/8][k] bitmask bytes --------------
__global__ __launch_bounds__(64) void snn_mask_build(const void* __restrict__ W,
                                                     const void* __restrict__ S,
                                                     unsigned char* __restrict__ MT) {
  __shared__ int flags_sh;
  const int tid = threadIdx.x;
  const int fl = sniff_flags(W, S, tid, &flags_sh);
  const bool s_bf = (fl & 2) != 0;
  const int tb = blockIdx.x;  // t-byte index: t = tb*8 + bit
  unsigned wrd[4] = {0u, 0u, 0u, 0u};
#pragma unroll
  for (int kk = 0; kk < 16; ++kk) {
    const int k = tid * 16 + kk;
    unsigned byte = 0;
    if (s_bf) {
      const unsigned short* Sb = (const unsigned short*)S;
      const uint4 u = *(const uint4*)&Sb[(size_t)k * SEQ_LEN + tb * 8];
      byte |= (((u.x & 0x7FFFu) != 0u) ? 1u : 0u) << 0;
      byte |= (((u.x & 0x7FFF0000u) != 0u) ? 1u : 0u) << 1;
      byte |= (((u.y & 0x7FFFu) != 0u) ? 1u : 0u) << 2;
      byte |= (((u.y & 0x7FFF0000u) != 0u) ? 1u : 0u) << 3;
      byte |= (((u.z & 0x7FFFu) != 0u) ? 1u : 0u) << 4;
      byte |= (((u.z & 0x7FFF0000u) != 0u) ? 1u : 0u) << 5;
      byte |= (((u.w & 0x7FFFu) != 0u) ? 1u : 0u) << 6;
      byte |= (((u.w & 0x7FFF0000u) != 0u) ? 1u : 0u) << 7;
    } else {
      const float* Sf = (const float*)S;
      const size_t base = (size_t)k * SEQ_LEN + tb * 8;
      const float4 f0 = *(const float4*)&Sf[base];
      const float4 f1 = *(const float4*)&Sf[base + 4];
      byte |= ((f0.x != 0.0f) ? 1u : 0u) << 0;
      byte |= ((f0.y != 0.0f) ? 1u : 0u) << 1;
      byte |= ((f0.z != 0.0f) ? 1u : 0u) << 2;
      byte |= ((f0.w != 0.0f) ? 1u : 0u) << 3;
      byte |= ((f1.x != 0.0f) ? 1u : 0u) << 4;
      byte |= ((f1.y != 0.0f) ? 1u : 0u) << 5;
      byte |= ((f1.z != 0.0f) ? 1u : 0u) << 6;
      byte |= ((f1.w != 0.0f) ? 1u : 0u) << 7;
    }
    wrd[kk >> 2] |= byte << ((kk & 3) * 8);
  }
  *(uint4*)&MT[(size_t)tb * N_PRE + tid * 16] =
      make_uint4(wrd[0], wrd[1], wrd[2], wrd[3]);
}

// ---------------- list build: MT -> per-t ascending spike list --------------
__global__ __launch_bounds__(64) void snn_list_build(const unsigned char* __restrict__ MT,
                                                     unsigned short* __restrict__ lists,
                                                     int* __restrict__ lens,
                                                     int* __restrict__ splits) {
  const int t = blockIdx.x;
  const int l = threadIdx.x;
  const unsigned char* Mrow = MT + (size_t)(t >> 3) * N_PRE;
  const int bit = t & 7;
  unsigned short* Lp = lists + (size_t)t * N_PRE;
  int base = 0;
  int split = 0;
#pragma unroll
  for (int c = 0; c < 16; ++c) {
    const int k = c * 64 + l;
    const int b = (Mrow[k] >> bit) & 1;
    const unsigned long long m = __ballot(b != 0);
    const int pre = __popcll(m & ((1ull << l) - 1ull));
    if (b) Lp[base + pre] = (unsigned short)k;
    base += __popcll(m);
    if (c == 7) split = base;
  }
  if (l == 0) {
    lens[t] = base;
    splits[t] = split;
  }
}

// ---------------- sparse GEMM: C[t][n] = sum over spiking k of WT[k][n] -----
// v12: 256-thr blocks = 4 waves = 4 consecutive t (same 256-n slice);
// slice = bid & 7 (XCD pinning, v11-verified: FETCH 130->12.4MB).
// BATCH16: 16 list entries -> 16 independent WT float4 loads in flight;
// adds strictly in ascending list order -> bit-identical chains.
__global__ __launch_bounds__(256) void snn_gemm_sp(const float* __restrict__ WT,
                                                   const unsigned short* __restrict__ lists,
                                                   const int* __restrict__ lens,
                                                   const int* __restrict__ splits,
                                                   float* __restrict__ C,
                                                   int t0, int ct) {
  const int slice = (int)blockIdx.x & 7;
  const int tq = (int)blockIdx.x >> 3;
  const int wid = (int)threadIdx.x >> 6;   // wave id 0..3 -> t offset
  const int lane = (int)threadIdx.x & 63;
  const int tl = tq * 4 + wid;
  const int tg = t0 + tl;
  const int n = slice * 256 + lane * 4;
  const unsigned short* __restrict__ L = lists + (size_t)tg * N_PRE;
  const int len = lens[tg];
  const int sp = splits[tg];
  float a0 = 0.f, a1 = 0.f, a2 = 0.f, a3 = 0.f;  // active chain accumulator
  float lo0, lo1, lo2, lo3;

#define SP_ADD(K)                                                      \
  {                                                                    \
    const float4 w = *(const float4*)&WT[((size_t)(K) << 11) + n];     \
    a0 += w.x; a1 += w.y; a2 += w.z; a3 += w.w;                        \
  }
#define SP_ACC(W_)                                                     \
  { a0 += W_.x; a1 += W_.y; a2 += W_.z; a3 += W_.w; }
#define SP_BATCH16(I)                                                  \
  {                                                                    \
    const uint4 u = *(const uint4*)&L[I];                              \
    const uint4 v = *(const uint4*)&L[(I) + 8];                        \
    const int k0 = u.x & 0xFFFF, k1 = u.x >> 16;                       \
    const int k2 = u.y & 0xFFFF, k3 = u.y >> 16;                       \
    const int k4 = u.z & 0xFFFF, k5 = u.z >> 16;                       \
    const int k6 = u.w & 0xFFFF, k7 = u.w >> 16;                       \
    const int k8 = v.x & 0xFFFF, k9 = v.x >> 16;                       \
    const int kA = v.y & 0xFFFF, kB = v.y >> 16;                       \
    const int kC = v.z & 0xFFFF, kD = v.z >> 16;                       \
    const int kE = v.w & 0xFFFF, kF = v.w >> 16;                       \
    const float4 w0 = *(const float4*)&WT[((size_t)k0 << 11) + n];     \
    const float4 w1 = *(const float4*)&WT[((size_t)k1 << 11) + n];     \
    const float4 w2 = *(const float4*)&WT[((size_t)k2 << 11) + n];     \
    const float4 w3 = *(const float4*)&WT[((size_t)k3 << 11) + n];     \
    const float4 w4 = *(const float4*)&WT[((size_t)k4 << 11) + n];     \
    const float4 w5 = *(const float4*)&WT[((size_t)k5 << 11) + n];     \
    const float4 w6 = *(const float4*)&WT[((size_t)k6 << 11) + n];     \
    const float4 w7 = *(const float4*)&WT[((size_t)k7 << 11) + n];     \
    const float4 w8 = *(const float4*)&WT[((size_t)k8 << 11) + n];     \
    const float4 w9 = *(const float4*)&WT[((size_t)k9 << 11) + n];     \
    const float4 wA = *(const float4*)&WT[((size_t)kA << 11) + n];     \
    const float4 wB = *(const float4*)&WT[((size_t)kB << 11) + n];     \
    const float4 wC = *(const float4*)&WT[((size_t)kC << 11) + n];     \
    const float4 wD = *(const float4*)&WT[((size_t)kD << 11) + n];     \
    const float4 wE = *(const float4*)&WT[((size_t)kE << 11) + n];     \
    const float4 wF = *(const float4*)&WT[((size_t)kF << 11) + n];     \
    SP_ACC(w0) SP_ACC(w1) SP_ACC(w2) SP_ACC(w3)                        \
    SP_ACC(w4) SP_ACC(w5) SP_ACC(w6) SP_ACC(w7)                        \
    SP_ACC(w8) SP_ACC(w9) SP_ACC(wA) SP_ACC(wB)                        \
    SP_ACC(wC) SP_ACC(wD) SP_ACC(wE) SP_ACC(wF)                        \
  }

  int i = 0;
  // ---- lo chain: k in [0, 512), list-ascending ----
  for (; i + 16 <= sp; i += 16) SP_BATCH16(i)
  for (; i < sp; ++i) SP_ADD(L[i])
  lo0 = a0; lo1 = a1; lo2 = a2; lo3 = a3;
  a0 = a1 = a2 = a3 = 0.f;
  // ---- hi chain: k in [512, 1024), list-ascending ----
  for (; i < len && (i & 7) != 0; ++i) SP_ADD(L[i])
  for (; i + 16 <= len; i += 16) SP_BATCH16(i)
  for (; i < len; ++i) SP_ADD(L[i])
#undef SP_BATCH16
#undef SP_ACC
#undef SP_ADD

  *(float4*)&C[(size_t)tl * N_POST + n] =
      make_float4(lo0 + a0, lo1 + a1, lo2 + a2, lo3 + a3);  // rn(S1+S2)
}

// ---------------- Scan phase 1: checkpoint chain (32 waves) -----------------
// v9: full-tile prefetch (64 loads in flight, verified: 158 -> off top-5).
// Chain ops and order identical to emit -> bitwise-equal v.
__global__ __launch_bounds__(64) void snn_scan_chk(const float* __restrict__ C,
                                                   float* __restrict__ vchk,
                                                   float* __restrict__ v_carry,
                                                   int ct, int first) {
  const int l = threadIdx.x;
  const int n = blockIdx.x * 64 + l;
  float v = 0.0f;
  if (!first) v = v_carry[n];
  const int ntiles = ct / 64;

  float cur[64], nxt[64];
#pragma unroll
  for (int j = 0; j < 64; ++j) cur[j] = C[(size_t)j * N_POST + n];

  for (int tile = 0; tile < ntiles; ++tile) {
    vchk[(size_t)tile * N_POST + n] = v;  // carry-in for this tile
    const int nb = (tile + 1) * 64;
    const bool hn = (tile + 1 < ntiles);
#pragma unroll
    for (int g = 0; g < 4; ++g) {
      // issue next-tile group g loads (independent of chain; 64 in flight
      // by end of tile, each covered by >=1 group of chain latency)
      if (hn) {
#pragma unroll
        for (int j = 0; j < 16; ++j)
          nxt[g * 16 + j] = C[(size_t)(nb + g * 16 + j) * N_POST + n];
      }
      // chain: 16 dependent LIF steps (DO NOT REORDER; identical to emit)
#pragma unroll
      for (int j = 0; j < 16; ++j) {
        const float c = cur[g * 16 + j];
        const float leak = opaque(v * 0.9f);  // rn(v*0.9f)
        v = leak + c;                         // rn(+c)
        const bool fired = (v >= 1.0f);
        v = fired ? 0.0f : v;
      }
    }
#pragma unroll
    for (int j = 0; j < 64; ++j) cur[j] = nxt[j];
  }
  v_carry[n] = v;
}

// ---------------- Scan phase 2: replay + emit (full chip) -------------------
// Block (n-group, tile): 1 wave, replays the 64-step chain from vchk with
// IDENTICAL ops/order (bitwise-equal s,v), stages in LDS [t][65]
// (chain writes bank (t+l)%32 conflict-free; flush reads 2-way = free),
// emits float4-wide on t. 2048 blocks -> full chip for the 64 MB of stores.
__global__ __launch_bounds__(64) void snn_scan_emit(const float* __restrict__ C,
                                                    const float* __restrict__ vchk,
                                                    float* __restrict__ spk,
                                                    float* __restrict__ vout,
                                                    int t0, int ct) {
  __shared__ float sb[64][65];
  __shared__ float vb[64][65];
  const int l = threadIdx.x;
  const int n0 = blockIdx.x * 64;
  const int tile = blockIdx.y;
  const int n = n0 + l;
  const int tb = tile * 64;

  float v = vchk[(size_t)tile * N_POST + n];

  float ccur[16], cnxt[16];
#pragma unroll
  for (int j = 0; j < 16; ++j) ccur[j] = C[(size_t)(tb + j) * N_POST + n];

#pragma unroll
  for (int g = 0; g < 4; ++g) {
    if (g < 3) {
#pragma unroll
      for (int j = 0; j < 16; ++j)
        cnxt[j] = C[(size_t)(tb + (g + 1) * 16 + j) * N_POST + n];
    }
    // chain: 16 dependent LIF steps (DO NOT REORDER; identical to chk)
#pragma unroll
    for (int j = 0; j < 16; ++j) {
      const float c = ccur[j];
      const float leak = opaque(v * 0.9f);  // rn(v*0.9f)
      v = leak + c;                         // rn(+c)
      const bool fired = (v >= 1.0f);
      sb[g * 16 + j][l] = fired ? 1.0f : 0.0f;
      v = fired ? 0.0f : v;
      vb[g * 16 + j][l] = v;
    }
#pragma unroll
    for (int j = 0; j < 16; ++j) ccur[j] = cnxt[j];
  }

  // flush: 16 iters x (4 rows x 16 lanes x float4-on-t); single wave =>
  // program order makes LDS writes visible, no barrier needed.
  const int t4 = (l & 15) * 4;
  const int rq = l >> 4;
  const size_t gtb = (size_t)t0 + tb;
#pragma unroll
  for (int it = 0; it < 16; ++it) {
    const int r = it * 4 + rq;  // neuron row within group
    float4 so, vo;
    so.x = sb[t4 + 0][r]; so.y = sb[t4 + 1][r];
    so.z = sb[t4 + 2][r]; so.w = sb[t4 + 3][r];
    vo.x = vb[t4 + 0][r]; vo.y = vb[t4 + 1][r];
    vo.z = vb[t4 + 2][r]; vo.w = vb[t4 + 3][r];
    const size_t go = (size_t)(n0 + r) * SEQ_LEN + gtb + t4;
    *(float4*)&spk[go] = so;
    *(float4*)&vout[go] = vo;
  }
}

// ---------------- fused fallback (ws too small), same [512|512] chain -------
__global__ __launch_bounds__(256) void snn_fused_blis(const void* __restrict__ W,
                                                      const void* __restrict__ S,
                                                      float* __restrict__ spk,
                                                      float* __restrict__ vout) {
  __shared__ float As[16][68];
  __shared__ float Bs[16][68];
  __shared__ float Ct[64][65];
  __shared__ float vsh[64];
  __shared__ int flags_sh;
  const int tid = threadIdx.x;
  const int fl = sniff_flags(W, S, tid, &flags_sh);
  const bool w_bf = (fl & 1) != 0;
  const bool s_bf = (fl & 2) != 0;

  const int tx = tid & 15;
  const int ty = tid >> 4;
  const int m0 = blockIdx.x * 64;
  if (tid < 64) vsh[tid] = 0.0f;

  for (int t0 = 0; t0 < SEQ_LEN; t0 += 64) {
    float acc0[4][4] = {{0.f}};
    float acc1[4][4] = {{0.f}};
    int k0 = 0;
#define FUSED_SEGMENT(ACC, KEND)                                                 \
    for (; k0 < (KEND); k0 += 16) {                                              \
      {                                                                          \
        const int r = tid >> 4, c = tid & 15;                                    \
        _Pragma("unroll") for (int j = 0; j < 4; ++j)                            \
            As[c][r + 16 * j] =                                                  \
                load_dyn(W, (size_t)(m0 + r + 16 * j) * N_PRE + k0 + c, w_bf);   \
      }                                                                          \
      {                                                                          \
        const int r = tid >> 6, c = tid & 63;                                    \
        _Pragma("unroll") for (int j = 0; j < 4; ++j)                            \
            Bs[r + 4 * j][c] =                                                   \
                load_dyn(S, (size_t)(k0 + r + 4 * j) * SEQ_LEN + t0 + c, s_bf);  \
      }                                                                          \
      __syncthreads();                                                           \
      _Pragma("unroll") for (int k = 0; k < 16; ++k) {                           \
        _Pragma("unroll") for (int i = 0; i < 4; ++i)                            \
            _Pragma("unroll") for (int j = 0; j < 4; ++j)                        \
                ACC[i][j] += As[k][ty * 4 + i] * Bs[k][tx * 4 + j];              \
      }                                                                          \
      __syncthreads();                                                           \
    }

    FUSED_SEGMENT(acc0, KSPLIT)
    FUSED_SEGMENT(acc1, N_PRE)
#undef FUSED_SEGMENT

#pragma unroll
    for (int i = 0; i < 4; ++i)
#pragma unroll
      for (int j = 0; j < 4; ++j) Ct[ty * 4 + i][tx * 4 + j] = acc0[i][j] + acc1[i][j];
    __syncthreads();
    if (tid < 64) {
      float v = vsh[tid];
#pragma unroll
      for (int k = 0; k < 64; ++k) {
        const float leak = opaque(v * 0.9f);
        v = leak + Ct[tid][k];
        const bool fired = (v >= 1.0f);
        const size_t g = (size_t)(m0 + tid) * SEQ_LEN + t0 + k;
        spk[g] = fired ? 1.0f : 0.0f;
        v = fired ? 0.0f : v;
        vout[g] = v;
      }
      vsh[tid] = v;
    }
    __syncthreads();
  }
}

extern "C" void kernel_launch(void* const* d_in, const int* in_sizes, int n_in,
                              void* d_out, int out_size, void* d_ws, size_t ws_size,
                              hipStream_t stream) {
  const void* stim = d_in[0];
  const void* weights = d_in[1];
  if (n_in >= 2 && in_sizes[0] == N_POST * N_PRE && in_sizes[1] == N_PRE * SEQ_LEN) {
    weights = d_in[0];
    stim = d_in[1];
  }

  float* spk = (float*)d_out;                    // output 0: spikes [N_POST, SEQ_LEN]
  float* vout = spk + (size_t)N_POST * SEQ_LEN;  // output 1: v      [N_POST, SEQ_LEN]

  // ---- workspace carve ----
  char* p = (char*)d_ws;
  float* WT = (float*)p;                 p += (size_t)N_PRE * N_POST * 4;      // 8 MB
  unsigned char* MT = (unsigned char*)p; p += (size_t)(SEQ_LEN / 8) * N_PRE;   // 512 KB
  unsigned short* lists = (unsigned short*)p; p += (size_t)SEQ_LEN * N_PRE * 2;// 8 MB
  int* lens = (int*)p;                   p += (size_t)SEQ_LEN * 4;             // 16 KB
  int* splits = (int*)p;                 p += (size_t)SEQ_LEN * 4;             // 16 KB
  float* v_carry = (float*)p;            p += (size_t)N_POST * 4;              // 8 KB
  float* vchk = (float*)p;               p += (size_t)(SEQ_LEN / 64) * N_POST * 4;  // 512 KB
  float* C = (float*)p;
  const size_t used = (size_t)(p - (char*)d_ws);
  const size_t remain = (ws_size > used) ? (ws_size - used) : 0;

  int chunkT = (int)((remain / ((size_t)N_POST * sizeof(float))) / 64 * 64);
  if (chunkT > SEQ_LEN) chunkT = SEQ_LEN;
  if (chunkT >= 64) {  // round to power of two so chunkT divides SEQ_LEN
    int pw = 64;
    while (pw * 2 <= chunkT && pw < SEQ_LEN) pw *= 2;
    chunkT = pw;
  }

  if (chunkT >= 64) {
    snn_wt_build<<<dim3(N_PRE / 64, N_POST / 64), dim3(256), 0, stream>>>(weights, stim, WT);
    snn_mask_build<<<dim3(SEQ_LEN / 8), dim3(64), 0, stream>>>(weights, stim, MT);
    snn_list_build<<<dim3(SEQ_LEN), dim3(64), 0, stream>>>(MT, lists, lens, splits);
    for (int t0 = 0; t0 < SEQ_LEN; t0 += chunkT) {
      const int ct = (SEQ_LEN - t0 < chunkT) ? (SEQ_LEN - t0) : chunkT;  // mult of 64
      snn_gemm_sp<<<dim3((ct / 4) * 8), dim3(256), 0, stream>>>(WT, lists, lens, splits,
                                                                C, t0, ct);
      snn_scan_chk<<<dim3(N_POST / 64), dim3(64), 0, stream>>>(C, vchk, v_carry,
                                                               ct, t0 == 0);
      snn_scan_emit<<<dim3(N_POST / 64, ct / 64), dim3(64), 0, stream>>>(C, vchk, spk,
                                                                         vout, t0, ct);
    }
  } else {
    snn_fused_blis<<<dim3(N_POST / 64), dim3(256), 0, stream>>>(weights, stim, spk, vout);
  }
}

// Round 14
// 349.129 us; speedup vs baseline: 1.0548x; 1.0548x over previous
//
#include <hip/hip_runtime.h>

#define N_PRE 1024
#define N_POST 2048
#define SEQ_LEN 4096

// Reference-verified numerics (R11 PASS): per C element two fp32 segment
// chains k in [0,512) and [512,1024), ascending, single accumulator each,
// combined rn(S1+S2). stim in {0,1} -> products exact -> FMA == mul+add.
// Scan: v = rn(rn(v*0.9f) + c), fire >= 1.0f, reset 0. DO NOT REORDER.
//
// Sparse (v6, PASS absmax 0.015625): skipping adds of exact +/-0.0 is
// BIT-IDENTICAL (acc starts +0.0; RN never yields -0.0 from a sum, so
// rn(acc + ±0) == acc). Walk the ascending per-t spike list: lo-chain k<512,
// hi-chain k>=512, write rn(lo+hi).
//
// v12 (PASS, 368us) REGRESSED gemm 125->144: BATCH16 + 256-thr blocks cut
// occupancy 77->44% without covering the serial list->WT address chain.
// v13: revert to 64-thr BATCH8 (v11-proven) + 2-deep register ping-pong:
// batch i+1's list word + 8 WT loads issued while batch i accumulates.
// Unified walk with dual accumulators and wave-uniform boundary branch:
// every element joins its original chain in list order -> bit-identical.
#define KSPLIT 512

__device__ __forceinline__ float opaque(float x) {
  asm volatile("" : "+v"(x));
  return x;
}

__device__ __forceinline__ float load_dyn(const void* p, size_t idx, bool isbf) {
  if (isbf) {
    const unsigned short b = ((const unsigned short*)p)[idx];
    return __uint_as_float(((unsigned int)b) << 16);
  }
  return ((const float*)p)[idx];
}

// Input-dtype sniff (established: weights fp32, stim bf16; kept for safety).
__device__ __forceinline__ int sniff_flags(const void* W, const void* S, int tid,
                                           int* flags_sh) {
  if (tid < 64) {
    const unsigned short* uw = (const unsigned short*)W;
    const float f = fabsf(__uint_as_float(((unsigned int)uw[tid * 2]) << 16));
    const bool big = !(f < 64.f);
    const unsigned long long wb = __ballot(big);
    const unsigned short* us = (const unsigned short*)S;
    int hit = 0;
    for (int j = 0; j < 64; ++j) hit |= (us[tid * 128 + 2 * j] == 0x3F80u) ? 1 : 0;
    const unsigned long long sb = __ballot(hit != 0);
    if (tid == 0) *flags_sh = ((wb == 0ull) ? 1 : 0) | ((sb != 0ull) ? 2 : 0);
  }
  __syncthreads();
  return *flags_sh;
}

// ---------------- WT build: W[n][k] -> WT[k][n] (fp32), LDS transpose -------
__global__ __launch_bounds__(256) void snn_wt_build(const void* __restrict__ W,
                                                    const void* __restrict__ S,
                                                    float* __restrict__ WT) {
  __shared__ float tile[64][65];
  __shared__ int flags_sh;
  const int tid = threadIdx.x;
  const int fl = sniff_flags(W, S, tid, &flags_sh);
  const bool w_bf = (fl & 1) != 0;
  const int k0 = blockIdx.x * 64;
  const int nn0 = blockIdx.y * 64;
  {
    const int r = tid >> 2;
    const int cq = tid & 3;
    if (!w_bf) {
      const float* Wf = (const float*)W;
#pragma unroll
      for (int p = 0; p < 4; ++p) {
        const int c = cq * 16 + p * 4;
        const float4 va = *(const float4*)&Wf[(size_t)(nn0 + r) * N_PRE + k0 + c];
        tile[c + 0][r] = va.x; tile[c + 1][r] = va.y;
        tile[c + 2][r] = va.z; tile[c + 3][r] = va.w;
      }
    } else {
#pragma unroll
      for (int p = 0; p < 4; ++p)
#pragma unroll
        for (int j = 0; j < 4; ++j) {
          const int c = cq * 16 + p * 4 + j;
          tile[c][r] = load_dyn(W, (size_t)(nn0 + r) * N_PRE + k0 + c, true);
        }
    }
  }
  __syncthreads();
  {
    const int kr = tid >> 2;
    const int nq = tid & 3;
#pragma unroll
    for (int p = 0; p < 4; ++p) {
      const int c = nq * 16 + p * 4;
      float4 o;
      o.x = tile[kr][c + 0]; o.y = tile[kr][c + 1];
      o.z = tile[kr][c + 2]; o.w = tile[kr][c + 3];
      *(float4*)&WT[(size_t)(k0 + kr) * N_POST + nn0 + c] = o;
    }
  }
}

// ---------------- mask build: stim -> MT[t/8][k] bitmask bytes --------------
__global__ __launch_bounds__(64) void snn_mask_build(const void* __restrict__ W,
                                                     const void* __restrict__ S,
                                                     unsigned char* __restrict__ MT) {
  __shared__ int flags_sh;
  const int tid = threadIdx.x;
  const int fl = sniff_flags(W, S, tid, &flags_sh);
  const bool s_bf = (fl & 2) != 0;
  const int tb = blockIdx.x;  // t-byte index: t = tb*8 + bit
  unsigned wrd[4] = {0u, 0u, 0u, 0u};
#pragma unroll
  for (int kk = 0; kk < 16; ++kk) {
    const int k = tid * 16 + kk;
    unsigned byte = 0;
    if (s_bf) {
      const unsigned short* Sb = (const unsigned short*)S;
      const uint4 u = *(const uint4*)&Sb[(size_t)k * SEQ_LEN + tb * 8];
      byte |= (((u.x & 0x7FFFu) != 0u) ? 1u : 0u) << 0;
      byte |= (((u.x & 0x7FFF0000u) != 0u) ? 1u : 0u) << 1;
      byte |= (((u.y & 0x7FFFu) != 0u) ? 1u : 0u) << 2;
      byte |= (((u.y & 0x7FFF0000u) != 0u) ? 1u : 0u) << 3;
      byte |= (((u.z & 0x7FFFu) != 0u) ? 1u : 0u) << 4;
      byte |= (((u.z & 0x7FFF0000u) != 0u) ? 1u : 0u) << 5;
      byte |= (((u.w & 0x7FFFu) != 0u) ? 1u : 0u) << 6;
      byte |= (((u.w & 0x7FFF0000u) != 0u) ? 1u : 0u) << 7;
    } else {
      const float* Sf = (const float*)S;
      const size_t base = (size_t)k * SEQ_LEN + tb * 8;
      const float4 f0 = *(const float4*)&Sf[base];
      const float4 f1 = *(const float4*)&Sf[base + 4];
      byte |= ((f0.x != 0.0f) ? 1u : 0u) << 0;
      byte |= ((f0.y != 0.0f) ? 1u : 0u) << 1;
      byte |= ((f0.z != 0.0f) ? 1u : 0u) << 2;
      byte |= ((f0.w != 0.0f) ? 1u : 0u) << 3;
      byte |= ((f1.x != 0.0f) ? 1u : 0u) << 4;
      byte |= ((f1.y != 0.0f) ? 1u : 0u) << 5;
      byte |= ((f1.z != 0.0f) ? 1u : 0u) << 6;
      byte |= ((f1.w != 0.0f) ? 1u : 0u) << 7;
    }
    wrd[kk >> 2] |= byte << ((kk & 3) * 8);
  }
  *(uint4*)&MT[(size_t)tb * N_PRE + tid * 16] =
      make_uint4(wrd[0], wrd[1], wrd[2], wrd[3]);
}

// ---------------- list build: MT -> per-t ascending spike list --------------
__global__ __launch_bounds__(64) void snn_list_build(const unsigned char* __restrict__ MT,
                                                     unsigned short* __restrict__ lists,
                                                     int* __restrict__ lens,
                                                     int* __restrict__ splits) {
  const int t = blockIdx.x;
  const int l = threadIdx.x;
  const unsigned char* Mrow = MT + (size_t)(t >> 3) * N_PRE;
  const int bit = t & 7;
  unsigned short* Lp = lists + (size_t)t * N_PRE;
  int base = 0;
  int split = 0;
#pragma unroll
  for (int c = 0; c < 16; ++c) {
    const int k = c * 64 + l;
    const int b = (Mrow[k] >> bit) & 1;
    const unsigned long long m = __ballot(b != 0);
    const int pre = __popcll(m & ((1ull << l) - 1ull));
    if (b) Lp[base + pre] = (unsigned short)k;
    base += __popcll(m);
    if (c == 7) split = base;
  }
  if (l == 0) {
    lens[t] = base;
    splits[t] = split;
  }
}

// ---------------- sparse GEMM: C[t][n] = sum over spiking k of WT[k][n] -----
// v13: 64-thr blocks (v11-proven occupancy), slice = bid & 7 (XCD pinning,
// FETCH 130->12.4MB verified). 2-deep register ping-pong: batch i+1's list
// word + 8 WT loads in flight while batch i accumulates. Unified walk, dual
// accumulators, wave-uniform boundary branch (list is lane-uniform; at most
// one batch straddles k=512). Every element joins its original chain in
// ascending list order -> bit-identical to the [512|512] dense chains.
__global__ __launch_bounds__(64) void snn_gemm_sp(const float* __restrict__ WT,
                                                  const unsigned short* __restrict__ lists,
                                                  const int* __restrict__ lens,
                                                  float* __restrict__ C,
                                                  int t0, int ct) {
  const int slice = (int)blockIdx.x & 7;
  const int tl = (int)blockIdx.x >> 3;
  const int tg = t0 + tl;
  const int n = slice * 256 + (int)threadIdx.x * 4;
  const unsigned short* __restrict__ L = lists + (size_t)tg * N_PRE;
  const int len = lens[tg];
  float lo0 = 0.f, lo1 = 0.f, lo2 = 0.f, lo3 = 0.f;
  float hi0 = 0.f, hi1 = 0.f, hi2 = 0.f, hi3 = 0.f;

  int kA0, kA1, kA2, kA3, kA4, kA5, kA6, kA7;
  int kB0, kB1, kB2, kB3, kB4, kB5, kB6, kB7;
  float4 wA0, wA1, wA2, wA3, wA4, wA5, wA6, wA7;
  float4 wB0, wB1, wB2, wB3, wB4, wB5, wB6, wB7;

#define ISSUE(S, I)                                                    \
  {                                                                    \
    const uint4 u = *(const uint4*)&L[I];                              \
    k##S##0 = u.x & 0xFFFF; k##S##1 = (int)(u.x >> 16);                \
    k##S##2 = u.y & 0xFFFF; k##S##3 = (int)(u.y >> 16);                \
    k##S##4 = u.z & 0xFFFF; k##S##5 = (int)(u.z >> 16);                \
    k##S##6 = u.w & 0xFFFF; k##S##7 = (int)(u.w >> 16);                \
    w##S##0 = *(const float4*)&WT[((size_t)k##S##0 << 11) + n];        \
    w##S##1 = *(const float4*)&WT[((size_t)k##S##1 << 11) + n];        \
    w##S##2 = *(const float4*)&WT[((size_t)k##S##2 << 11) + n];        \
    w##S##3 = *(const float4*)&WT[((size_t)k##S##3 << 11) + n];        \
    w##S##4 = *(const float4*)&WT[((size_t)k##S##4 << 11) + n];        \
    w##S##5 = *(const float4*)&WT[((size_t)k##S##5 << 11) + n];        \
    w##S##6 = *(const float4*)&WT[((size_t)k##S##6 << 11) + n];        \
    w##S##7 = *(const float4*)&WT[((size_t)k##S##7 << 11) + n];        \
  }
#define ACC_LO(W_) { lo0 += W_.x; lo1 += W_.y; lo2 += W_.z; lo3 += W_.w; }
#define ACC_HI(W_) { hi0 += W_.x; hi1 += W_.y; hi2 += W_.z; hi3 += W_.w; }
#define ACC_SEL(K_, W_)                                                \
  { if ((K_) < KSPLIT) ACC_LO(W_) else ACC_HI(W_) }
#define ACCUM(S)                                                       \
  {                                                                    \
    if (k##S##7 < KSPLIT) {                                            \
      ACC_LO(w##S##0) ACC_LO(w##S##1) ACC_LO(w##S##2) ACC_LO(w##S##3)  \
      ACC_LO(w##S##4) ACC_LO(w##S##5) ACC_LO(w##S##6) ACC_LO(w##S##7)  \
    } else if (k##S##0 >= KSPLIT) {                                    \
      ACC_HI(w##S##0) ACC_HI(w##S##1) ACC_HI(w##S##2) ACC_HI(w##S##3)  \
      ACC_HI(w##S##4) ACC_HI(w##S##5) ACC_HI(w##S##6) ACC_HI(w##S##7)  \
    } else {                                                           \
      ACC_SEL(k##S##0, w##S##0) ACC_SEL(k##S##1, w##S##1)              \
      ACC_SEL(k##S##2, w##S##2) ACC_SEL(k##S##3, w##S##3)              \
      ACC_SEL(k##S##4, w##S##4) ACC_SEL(k##S##5, w##S##5)              \
      ACC_SEL(k##S##6, w##S##6) ACC_SEL(k##S##7, w##S##7)              \
    }                                                                  \
  }

  const int len8 = len & ~7;
  const int nb = len8 >> 3;
  if (nb > 0) {
    ISSUE(A, 0)
    int b = 0;
    for (; b + 2 <= nb; b += 2) {
      ISSUE(B, (b + 1) * 8)
      ACCUM(A)                              // B's loads fly over A's adds
      if (b + 2 < nb) ISSUE(A, (b + 2) * 8)
      ACCUM(B)                              // A's loads fly over B's adds
    }
    if (b < nb) ACCUM(A)  // odd final batch (already issued)
  }
  for (int i = len8; i < len; ++i) {  // tail, ascending, uniform branch
    const int k = L[i];
    const float4 w = *(const float4*)&WT[((size_t)k << 11) + n];
    ACC_SEL(k, w)
  }
#undef ACCUM
#undef ACC_SEL
#undef ACC_HI
#undef ACC_LO
#undef ISSUE

  *(float4*)&C[(size_t)tl * N_POST + n] =
      make_float4(lo0 + hi0, lo1 + hi1, lo2 + hi2, lo3 + hi3);  // rn(S1+S2)
}

// ---------------- Scan phase 1: checkpoint chain (32 waves) -----------------
// v9: full-tile prefetch (64 loads in flight, verified: 158 -> off top-5).
// Chain ops and order identical to emit -> bitwise-equal v.
__global__ __launch_bounds__(64) void snn_scan_chk(const float* __restrict__ C,
                                                   float* __restrict__ vchk,
                                                   float* __restrict__ v_carry,
                                                   int ct, int first) {
  const int l = threadIdx.x;
  const int n = blockIdx.x * 64 + l;
  float v = 0.0f;
  if (!first) v = v_carry[n];
  const int ntiles = ct / 64;

  float cur[64], nxt[64];
#pragma unroll
  for (int j = 0; j < 64; ++j) cur[j] = C[(size_t)j * N_POST + n];

  for (int tile = 0; tile < ntiles; ++tile) {
    vchk[(size_t)tile * N_POST + n] = v;  // carry-in for this tile
    const int nb = (tile + 1) * 64;
    const bool hn = (tile + 1 < ntiles);
#pragma unroll
    for (int g = 0; g < 4; ++g) {
      // issue next-tile group g loads (independent of chain; 64 in flight
      // by end of tile, each covered by >=1 group of chain latency)
      if (hn) {
#pragma unroll
        for (int j = 0; j < 16; ++j)
          nxt[g * 16 + j] = C[(size_t)(nb + g * 16 + j) * N_POST + n];
      }
      // chain: 16 dependent LIF steps (DO NOT REORDER; identical to emit)
#pragma unroll
      for (int j = 0; j < 16; ++j) {
        const float c = cur[g * 16 + j];
        const float leak = opaque(v * 0.9f);  // rn(v*0.9f)
        v = leak + c;                         // rn(+c)
        const bool fired = (v >= 1.0f);
        v = fired ? 0.0f : v;
      }
    }
#pragma unroll
    for (int j = 0; j < 64; ++j) cur[j] = nxt[j];
  }
  v_carry[n] = v;
}

// ---------------- Scan phase 2: replay + emit (full chip) -------------------
// Block (n-group, tile): 1 wave, replays the 64-step chain from vchk with
// IDENTICAL ops/order (bitwise-equal s,v), stages in LDS [t][65]
// (chain writes bank (t+l)%32 conflict-free; flush reads 2-way = free),
// emits float4-wide on t. 2048 blocks -> full chip for the 64 MB of stores.
__global__ __launch_bounds__(64) void snn_scan_emit(const float* __restrict__ C,
                                                    const float* __restrict__ vchk,
                                                    float* __restrict__ spk,
                                                    float* __restrict__ vout,
                                                    int t0, int ct) {
  __shared__ float sb[64][65];
  __shared__ float vb[64][65];
  const int l = threadIdx.x;
  const int n0 = blockIdx.x * 64;
  const int tile = blockIdx.y;
  const int n = n0 + l;
  const int tb = tile * 64;

  float v = vchk[(size_t)tile * N_POST + n];

  float ccur[16], cnxt[16];
#pragma unroll
  for (int j = 0; j < 16; ++j) ccur[j] = C[(size_t)(tb + j) * N_POST + n];

#pragma unroll
  for (int g = 0; g < 4; ++g) {
    if (g < 3) {
#pragma unroll
      for (int j = 0; j < 16; ++j)
        cnxt[j] = C[(size_t)(tb + (g + 1) * 16 + j) * N_POST + n];
    }
    // chain: 16 dependent LIF steps (DO NOT REORDER; identical to chk)
#pragma unroll
    for (int j = 0; j < 16; ++j) {
      const float c = ccur[j];
      const float leak = opaque(v * 0.9f);  // rn(v*0.9f)
      v = leak + c;                         // rn(+c)
      const bool fired = (v >= 1.0f);
      sb[g * 16 + j][l] = fired ? 1.0f : 0.0f;
      v = fired ? 0.0f : v;
      vb[g * 16 + j][l] = v;
    }
#pragma unroll
    for (int j = 0; j < 16; ++j) ccur[j] = cnxt[j];
  }

  // flush: 16 iters x (4 rows x 16 lanes x float4-on-t); single wave =>
  // program order makes LDS writes visible, no barrier needed.
  const int t4 = (l & 15) * 4;
  const int rq = l >> 4;
  const size_t gtb = (size_t)t0 + tb;
#pragma unroll
  for (int it = 0; it < 16; ++it) {
    const int r = it * 4 + rq;  // neuron row within group
    float4 so, vo;
    so.x = sb[t4 + 0][r]; so.y = sb[t4 + 1][r];
    so.z = sb[t4 + 2][r]; so.w = sb[t4 + 3][r];
    vo.x = vb[t4 + 0][r]; vo.y = vb[t4 + 1][r];
    vo.z = vb[t4 + 2][r]; vo.w = vb[t4 + 3][r];
    const size_t go = (size_t)(n0 + r) * SEQ_LEN + gtb + t4;
    *(float4*)&spk[go] = so;
    *(float4*)&vout[go] = vo;
  }
}

// ---------------- fused fallback (ws too small), same [512|512] chain -------
__global__ __launch_bounds__(256) void snn_fused_blis(const void* __restrict__ W,
                                                      const void* __restrict__ S,
                                                      float* __restrict__ spk,
                                                      float* __restrict__ vout) {
  __shared__ float As[16][68];
  __shared__ float Bs[16][68];
  __shared__ float Ct[64][65];
  __shared__ float vsh[64];
  __shared__ int flags_sh;
  const int tid = threadIdx.x;
  const int fl = sniff_flags(W, S, tid, &flags_sh);
  const bool w_bf = (fl & 1) != 0;
  const bool s_bf = (fl & 2) != 0;

  const int tx = tid & 15;
  const int ty = tid >> 4;
  const int m0 = blockIdx.x * 64;
  if (tid < 64) vsh[tid] = 0.0f;

  for (int t0 = 0; t0 < SEQ_LEN; t0 += 64) {
    float acc0[4][4] = {{0.f}};
    float acc1[4][4] = {{0.f}};
    int k0 = 0;
#define FUSED_SEGMENT(ACC, KEND)                                                 \
    for (; k0 < (KEND); k0 += 16) {                                              \
      {                                                                          \
        const int r = tid >> 4, c = tid & 15;                                    \
        _Pragma("unroll") for (int j = 0; j < 4; ++j)                            \
            As[c][r + 16 * j] =                                                  \
                load_dyn(W, (size_t)(m0 + r + 16 * j) * N_PRE + k0 + c, w_bf);   \
      }                                                                          \
      {                                                                          \
        const int r = tid >> 6, c = tid & 63;                                    \
        _Pragma("unroll") for (int j = 0; j < 4; ++j)                            \
            Bs[r + 4 * j][c] =                                                   \
                load_dyn(S, (size_t)(k0 + r + 4 * j) * SEQ_LEN + t0 + c, s_bf);  \
      }                                                                          \
      __syncthreads();                                                           \
      _Pragma("unroll") for (int k = 0; k < 16; ++k) {                           \
        _Pragma("unroll") for (int i = 0; i < 4; ++i)                            \
            _Pragma("unroll") for (int j = 0; j < 4; ++j)                        \
                ACC[i][j] += As[k][ty * 4 + i] * Bs[k][tx * 4 + j];              \
      }                                                                          \
      __syncthreads();                                                           \
    }

    FUSED_SEGMENT(acc0, KSPLIT)
    FUSED_SEGMENT(acc1, N_PRE)
#undef FUSED_SEGMENT

#pragma unroll
    for (int i = 0; i < 4; ++i)
#pragma unroll
      for (int j = 0; j < 4; ++j) Ct[ty * 4 + i][tx * 4 + j] = acc0[i][j] + acc1[i][j];
    __syncthreads();
    if (tid < 64) {
      float v = vsh[tid];
#pragma unroll
      for (int k = 0; k < 64; ++k) {
        const float leak = opaque(v * 0.9f);
        v = leak + Ct[tid][k];
        const bool fired = (v >= 1.0f);
        const size_t g = (size_t)(m0 + tid) * SEQ_LEN + t0 + k;
        spk[g] = fired ? 1.0f : 0.0f;
        v = fired ? 0.0f : v;
        vout[g] = v;
      }
      vsh[tid] = v;
    }
    __syncthreads();
  }
}

extern "C" void kernel_launch(void* const* d_in, const int* in_sizes, int n_in,
                              void* d_out, int out_size, void* d_ws, size_t ws_size,
                              hipStream_t stream) {
  const void* stim = d_in[0];
  const void* weights = d_in[1];
  if (n_in >= 2 && in_sizes[0] == N_POST * N_PRE && in_sizes[1] == N_PRE * SEQ_LEN) {
    weights = d_in[0];
    stim = d_in[1];
  }

  float* spk = (float*)d_out;                    // output 0: spikes [N_POST, SEQ_LEN]
  float* vout = spk + (size_t)N_POST * SEQ_LEN;  // output 1: v      [N_POST, SEQ_LEN]

  // ---- workspace carve ----
  char* p = (char*)d_ws;
  float* WT = (float*)p;                 p += (size_t)N_PRE * N_POST * 4;      // 8 MB
  unsigned char* MT = (unsigned char*)p; p += (size_t)(SEQ_LEN / 8) * N_PRE;   // 512 KB
  unsigned short* lists = (unsigned short*)p; p += (size_t)SEQ_LEN * N_PRE * 2;// 8 MB
  int* lens = (int*)p;                   p += (size_t)SEQ_LEN * 4;             // 16 KB
  int* splits = (int*)p;                 p += (size_t)SEQ_LEN * 4;             // 16 KB
  float* v_carry = (float*)p;            p += (size_t)N_POST * 4;              // 8 KB
  float* vchk = (float*)p;               p += (size_t)(SEQ_LEN / 64) * N_POST * 4;  // 512 KB
  float* C = (float*)p;
  const size_t used = (size_t)(p - (char*)d_ws);
  const size_t remain = (ws_size > used) ? (ws_size - used) : 0;

  int chunkT = (int)((remain / ((size_t)N_POST * sizeof(float))) / 64 * 64);
  if (chunkT > SEQ_LEN) chunkT = SEQ_LEN;
  if (chunkT >= 64) {  // round to power of two so chunkT divides SEQ_LEN
    int pw = 64;
    while (pw * 2 <= chunkT && pw < SEQ_LEN) pw *= 2;
    chunkT = pw;
  }

  if (chunkT >= 64) {
    snn_wt_build<<<dim3(N_PRE / 64, N_POST / 64), dim3(256), 0, stream>>>(weights, stim, WT);
    snn_mask_build<<<dim3(SEQ_LEN / 8), dim3(64), 0, stream>>>(weights, stim, MT);
    snn_list_build<<<dim3(SEQ_LEN), dim3(64), 0, stream>>>(MT, lists, lens, splits);
    for (int t0 = 0; t0 < SEQ_LEN; t0 += chunkT) {
      const int ct = (SEQ_LEN - t0 < chunkT) ? (SEQ_LEN - t0) : chunkT;  // mult of 64
      snn_gemm_sp<<<dim3(ct * 8), dim3(64), 0, stream>>>(WT, lists, lens, C, t0, ct);
      snn_scan_chk<<<dim3(N_POST / 64), dim3(64), 0, stream>>>(C, vchk, v_carry,
                                                               ct, t0 == 0);
      snn_scan_emit<<<dim3(N_POST / 64, ct / 64), dim3(64), 0, stream>>>(C, vchk, spk,
                                                                         vout, t0, ct);
    }
  } else {
    snn_fused_blis<<<dim3(N_POST / 64), dim3(256), 0, stream>>>(weights, stim, spk, vout);
  }
}